// Round 9
// baseline (11158.878 us; speedup 1.0000x reference)
//
#include <hip/hip_runtime.h>
#include <stdint.h>

// Producer/consumer binary conv, round 9. ONE dispatch, three block roles:
//   bid 0:        pack weights (u64 bitmasks) + 9x64 boundary bases table
//   bid 1..224:   act producers — each packs a 16-row group of one image into
//                 the zero-padded packed buffer, then RELEASE-sets its flag
//   bid 225..1792: consumers — R4's harness-proven conv (4px x 16 o / thread),
//                 each thread ACQUIRE-spins on the <=2 flags covering rows h-1..h+1
// All 1793 blocks are co-resident by construction (__launch_bounds__(256,8)
// => <=64 VGPR => 8 blocks/CU => 2048 capacity), so producers always run and
// spin cannot deadlock; spin is bounded anyway. Flags zeroed per launch via
// hipMemsetAsync. sign(x) bit = signbit(x); dot = 64 - 2*popc(a^w); zero halo
// words (bits 0 = all +1) with pad contribution folded into bases[class][o].

#define NN 32
#define CC 64
#define HH 112
#define WW 112
#define OO 64
#define HW (HH*WW)        // 12544
#define HP (HW/2)         // 6272 u64-pairs per channel plane
#define G4 (HW/4)         // 3136 quads per image

#define PW 116            // padded width in u64 words (2 left, 2 right)
#define PH 114            // padded height (1 top, 1 bottom)
#define PHW (PW*PH)       // 13224 words per image

#define BLK 256
#define NGRP 7                      // 16-row groups per image
#define PROD (NN*NGRP)              // 224 act-producer blocks
#define CONS ((NN*G4/BLK)*4)        // 1568 consumer blocks (o-split x4)
#define GRID (1 + PROD + CONS)      // 1793 <= 2048 capacity

#define AGT __HIP_MEMORY_SCOPE_AGENT

typedef float f4v __attribute__((ext_vector_type(4)));

// workspace layout (u64 words): [0,576) wp | [576,864) basesg f32[9][64]
// flags: bytes [8192, 8192+4*225) | ap: words [2048, 2048+NN*PHW)

__global__ __launch_bounds__(BLK, 8)
void pc_kernel(const float* __restrict__ act, const float* __restrict__ wgt,
               uint64_t* __restrict__ ap, uint64_t* __restrict__ wp,
               float* __restrict__ basesg, uint32_t* __restrict__ flags,
               float* __restrict__ out) {
    const int bid = blockIdx.x;
    const int tid = threadIdx.x;

    if (bid == 0) {
        // ================= weight block =================
        for (int u = tid; u < OO * 9; u += BLK) {
            const int o = u / 9, k = u - o * 9;
            uint32_t lo = 0, hi = 0;
            #pragma unroll
            for (int i = 0; i < 64; ++i) {
                const uint32_t s = __float_as_uint(wgt[(o * 64 + i) * 9 + k]) >> 31;
                if (i < 32) lo |= s << i;
                else        hi |= s << (i - 32);
            }
            wp[u] = ((uint64_t)hi << 32) | lo;
        }
        __syncthreads();
        if (tid < OO) {
            const int o = tid;
            int contrib[9];
            #pragma unroll
            for (int k = 0; k < 9; ++k)
                contrib[k] = 64 - 2 * (int)__popcll(wp[o * 9 + k]);
            #pragma unroll
            for (int ht = 0; ht < 3; ++ht) {
                #pragma unroll
                for (int wt = 0; wt < 3; ++wt) {
                    int sum = 0;
                    #pragma unroll
                    for (int k = 0; k < 9; ++k) {
                        const int kh = k / 3, kw = k - kh * 3;
                        const bool inv = (ht == 0 && kh == 0) || (ht == 2 && kh == 2) ||
                                         (wt == 0 && kw == 0) || (wt == 2 && kw == 2);
                        if (inv) sum += contrib[k];
                    }
                    basesg[(ht * 3 + wt) * OO + o] = (float)(576 - sum);
                }
            }
        }
        __syncthreads();
        if (tid == 0) __hip_atomic_store(&flags[0], 1u, __ATOMIC_RELEASE, AGT);
        return;
    }

    if (bid <= PROD) {
        // ================= act producer: one 16-row group =================
        const int pb = bid - 1;
        const int n = pb / NGRP;
        const int g16 = pb - n * NGRP;
        uint64_t* apn = ap + (size_t)n * PHW;

        // halo words this group owns (zeroed before flag release)
        if (tid < 64) {                          // side cols of the 16 padded rows
            const int pr = g16 * 16 + 1 + (tid >> 2);
            const int sc = tid & 3;
            const int col = (sc < 2) ? sc : 112 + sc;      // 0,1,114,115
            apn[(size_t)pr * PW + col] = 0ull;
        }
        if (g16 == 0 && tid < PW)       apn[tid] = 0ull;               // padded row 0
        if (g16 == NGRP - 1 && tid < PW) apn[(size_t)(PH - 1) * PW + tid] = 0ull;

        // pack 16 rows x 112 px, 2 px per unit (R3-proven logic)
        for (int u = tid; u < 16 * 56; u += BLK) {
            const int r = u / 56;
            const int w2 = u - r * 56;
            const int h = g16 * 16 + r;
            const uint64_t* bp = (const uint64_t*)act + (size_t)n * CC * HP
                               + (size_t)h * 56 + w2;
            uint32_t lo0 = 0, lo1 = 0, hi0 = 0, hi1 = 0;
            #pragma unroll
            for (int c = 0; c < 64; ++c) {
                const uint64_t v = bp[(size_t)c * HP];     // 64 independent 8B loads
                const uint32_t s0 = (uint32_t)(v >> 31) & 1u;
                const uint32_t s1 = (uint32_t)(v >> 63);
                if (c < 32) { lo0 |= s0 << c;        lo1 |= s1 << c; }
                else        { hi0 |= s0 << (c - 32); hi1 |= s1 << (c - 32); }
            }
            ulonglong2 v;
            v.x = ((uint64_t)hi0 << 32) | lo0;
            v.y = ((uint64_t)hi1 << 32) | lo1;
            // image px (h, 2*w2+j) -> padded (h+1, 2*w2+2+j); 16B aligned
            *(ulonglong2*)(apn + (size_t)(h + 1) * PW + (2 * w2 + 2)) = v;
        }

        __syncthreads();                         // all stores drained (vmcnt 0)
        if (tid == 0)
            __hip_atomic_store(&flags[1 + pb], 1u, __ATOMIC_RELEASE, AGT);
        return;
    }

    // ================= consumer: R4 conv, flag-gated =================
    const int cb = bid - 1 - PROD;
    const int og = cb & 3;                       // o-group (uniform per block)
    const int gb = cb >> 2;
    const int t = gb * BLK + tid;                // 4px-quad id over N*HW/4
    const int n = t / G4;
    const int g = t - n * G4;
    const int h = g / (WW / 4);
    const int w4 = g - h * (WW / 4);
    const int w0 = 4 * w4;

    // flags covering packed rows h-1..h+1 of image n
    const int r_lo = (h > 0) ? h - 1 : 0;
    const int r_hi = (h < HH - 1) ? h + 1 : HH - 1;
    const int f1 = 1 + n * NGRP + (r_lo >> 4);
    const int f2 = 1 + n * NGRP + (r_hi >> 4);
    int guard = 1 << 22;                         // bounded: no hang possible
    for (;;) {
        const bool ok =
            __hip_atomic_load(&flags[0], __ATOMIC_ACQUIRE, AGT) &&
            __hip_atomic_load(&flags[f1], __ATOMIC_ACQUIRE, AGT) &&
            (f2 == f1 || __hip_atomic_load(&flags[f2], __ATOMIC_ACQUIRE, AGT));
        if (ok || --guard <= 0) break;
        __builtin_amdgcn_s_sleep(8);
    }

    // taps: padded rows h..h+2, cols w0..w0+7 (16B-aligned ulonglong2 loads)
    uint64_t A[3][8];
    const uint64_t* rb = ap + (size_t)n * PHW + (size_t)h * PW + w0;
    #pragma unroll
    for (int r = 0; r < 3; ++r) {
        const ulonglong2* p = (const ulonglong2*)(rb + (size_t)r * PW);
        const ulonglong2 u0 = p[0], u1 = p[1], u2 = p[2], u3 = p[3];
        A[r][0] = u0.x; A[r][1] = u0.y; A[r][2] = u1.x; A[r][3] = u1.y;
        A[r][4] = u2.x; A[r][5] = u2.y; A[r][6] = u3.x; A[r][7] = u3.y;
    }

    const int ht = (h == 0) ? 0 : ((h == HH - 1) ? 2 : 1);
    const float* bp0  = basesg + (ht * 3 + ((w0 == 0) ? 0 : 1)) * OO;
    const float* bp12 = basesg + (ht * 3 + 1) * OO;
    const float* bp3  = basesg + (ht * 3 + ((w0 + 3 == WW - 1) ? 2 : 1)) * OO;

    float* op = out + (size_t)n * (OO * HW) + (size_t)h * WW + w0;
    const int o0 = og * 16;
    #pragma unroll 2
    for (int o = o0; o < o0 + 16; ++o) {
        const uint64_t* wk = wp + o * 9;         // wave-uniform -> scalar loads
        int s0 = 0, s1 = 0, s2 = 0, s3 = 0;
        #pragma unroll
        for (int kh = 0; kh < 3; ++kh) {
            #pragma unroll
            for (int kw = 0; kw < 3; ++kw) {
                const uint64_t wv = wk[kh * 3 + kw];
                // px j tap kw -> padded col w0+1+j+kw -> A[kh][1+j+kw]
                s0 += __popcll(A[kh][kw + 1] ^ wv);
                s1 += __popcll(A[kh][kw + 2] ^ wv);
                s2 += __popcll(A[kh][kw + 3] ^ wv);
                s3 += __popcll(A[kh][kw + 4] ^ wv);
            }
        }
        f4v v;
        v.x = bp0[o]  - 2.0f * (float)s0;
        v.y = bp12[o] - 2.0f * (float)s1;
        v.z = bp12[o] - 2.0f * (float)s2;
        v.w = bp3[o]  - 2.0f * (float)s3;
        __builtin_nontemporal_store(v, (f4v*)(op + (size_t)o * HW));  // never re-read
    }
}

extern "C" void kernel_launch(void* const* d_in, const int* in_sizes, int n_in,
                              void* d_out, int out_size, void* d_ws, size_t ws_size,
                              hipStream_t stream) {
    const float* act = (const float*)d_in[0];
    const float* wgt = (const float*)d_in[1];
    float* out = (float*)d_out;

    uint64_t* wp = (uint64_t*)d_ws;                        // [0,576)
    float* basesg = (float*)(wp + 576);                    // 576 f32
    uint32_t* flags = (uint32_t*)((char*)d_ws + 8192);     // 225 u32
    uint64_t* apb = wp + 2048;                             // 32*13224 words ~3.39MB

    hipMemsetAsync((void*)flags, 0, 1024, stream);         // stream-ordered, capture-safe
    pc_kernel<<<GRID, BLK, 0, stream>>>(act, wgt, apb, wp, basesg, flags, out);
}

// Round 10
// 217.241 us; speedup vs baseline: 51.3664x; 51.3664x over previous
//
#include <hip/hip_runtime.h>
#include <stdint.h>

// Fused binary conv, round 10 = R7 (verified) with three targeted changes:
//  (1) output stores are PLAIN (not nontemporal): each block writes only
//      ~3 KB per o-plane; NT bypassed L2 write-combining -> scattered-KB HBM
//      writes. Plain path lets L2 merge (fills prove it sustains 6.7 TB/s).
//  (2) BAND 4->7: halo re-read 1.5x->1.29x, per-plane contiguity 1.8->3.1 KB,
//      grid 512 = exactly 2 blocks/CU.
//  (3) exact-cover item mapping for the new shape (guarded tail iters).
// Everything else (prepack, byte-matrix tile, conv inner loop) is R7 verbatim.
// sign(x) bit = signbit(x); dot over 64 ch = 64 - 2*popc(a ^ w); zero halo
// (bits 0 = all +1) with pad contribution folded into bases[class][o].

#define NN 32
#define CC 64
#define HH 112
#define WW 112
#define OO 64
#define HW (HH*WW)        // 12544
#define G4 (HW/4)         // 3136 quads per channel plane

#define BAND 7
#define NBAND (HH/BAND)   // 16
#define GRID (NN*NBAND)   // 512 blocks = 2.0 per CU
#define BLK 448           // 7 waves

#define TROWS (BAND+2)    // 9 tile rows: image rows h0-1 .. h0+7
#define TCOLS 114         // halo col + 112 + halo col

#define PITEMS (TROWS*8*28)   // 2016 pack items (row, ch-eighth, quad)
#define CITEMS (4*BAND*28)    // 784 conv items (o-group, row, quad)

typedef float f4v __attribute__((ext_vector_type(4)));

// workspace (u64 words): [0,576) wp | [1024,1312) basesg (f32[9][64])

__global__ __launch_bounds__(576)
void prepack_kernel(const float* __restrict__ wgt, uint64_t* __restrict__ wp,
                    float* __restrict__ basesg) {
    __shared__ uint64_t wl[OO * 9];
    const int t = threadIdx.x;                   // 0..575
    {
        const int o = t / 9, k = t - o * 9;
        uint32_t lo = 0, hi = 0;
        #pragma unroll
        for (int i = 0; i < 64; ++i) {
            const uint32_t s = __float_as_uint(wgt[(o * 64 + i) * 9 + k]) >> 31;
            if (i < 32) lo |= s << i;
            else        hi |= s << (i - 32);
        }
        const uint64_t w = ((uint64_t)hi << 32) | lo;
        wl[t] = w;
        wp[t] = w;
    }
    __syncthreads();
    if (t < OO) {
        const int o = t;
        int contrib[9];
        #pragma unroll
        for (int k = 0; k < 9; ++k)
            contrib[k] = 64 - 2 * (int)__popcll(wl[o * 9 + k]);
        #pragma unroll
        for (int ht = 0; ht < 3; ++ht) {
            #pragma unroll
            for (int wt = 0; wt < 3; ++wt) {
                int sum = 0;
                #pragma unroll
                for (int k = 0; k < 9; ++k) {
                    const int kh = k / 3, kw = k - kh * 3;
                    const bool inv = (ht == 0 && kh == 0) || (ht == 2 && kh == 2) ||
                                     (wt == 0 && kw == 0) || (wt == 2 && kw == 2);
                    if (inv) sum += contrib[k];
                }
                basesg[(ht * 3 + wt) * OO + o] = (float)(576 - sum);
            }
        }
    }
}

__global__ __launch_bounds__(BLK)
void fused_kernel(const float* __restrict__ act, const uint64_t* __restrict__ wp,
                  const float* __restrict__ basesg, float* __restrict__ out) {
    __shared__ uint8_t  sm[TROWS][TCOLS][8];     // 8208 B byte-matrix tile
    __shared__ uint64_t wlds[OO * 9];            // 4608 B packed weights
    __shared__ float    basesl[9 * OO];          // 2304 B

    const int b = blockIdx.x;
    const int n = b >> 4;                        // NBAND = 16
    const int band = b & 15;
    const int h0 = band * BAND;
    const int tid = threadIdx.x;

    // ---- copy precomputed tables (L2-resident ~7KB) ----
    for (int t2 = tid; t2 < OO * 9; t2 += BLK) {
        wlds[t2] = wp[t2];
        basesl[t2] = basesg[t2];
    }

    // ---- zero side-halo cols (never written by pack) ----
    if (tid < 2 * TROWS) {
        const int r = tid >> 1, c = (tid & 1) ? 113 : 0;
        *(uint64_t*)&sm[r][c][0] = 0ull;
    }

    // ---- pack act tile: item = (row r, ch-eighth e, quad q), guarded tail ----
    #pragma unroll
    for (int it = 0; it < 5; ++it) {
        const int item = tid + it * BLK;         // 0..2239, valid < 2016
        if (item < PITEMS) {
            const int pr = item / 224;           // 0..8 tile row
            const int rem = item - pr * 224;
            const int e = rem / 28;              // 0..7 channel-eighth
            const int q = rem - e * 28;          // 0..27 quad
            const int h = h0 - 1 + pr;           // absolute image row
            uint32_t b0 = 0, b1 = 0, b2 = 0, b3 = 0;
            if ((unsigned)h < (unsigned)HH) {
                const uint4* bp = (const uint4*)act + ((size_t)n * CC + e * 8) * G4
                                + (size_t)h * 28 + q;
                #pragma unroll
                for (int j = 0; j < 8; ++j) {    // 8 independent 16B loads
                    const uint4 v = bp[(size_t)j * G4];
                    b0 |= (v.x >> 31) << j; b1 |= (v.y >> 31) << j;
                    b2 |= (v.z >> 31) << j; b3 |= (v.w >> 31) << j;
                }
            }
            sm[pr][4 * q + 1][e] = (uint8_t)b0;  // byte e = channels 8e..8e+7
            sm[pr][4 * q + 2][e] = (uint8_t)b1;
            sm[pr][4 * q + 3][e] = (uint8_t)b2;
            sm[pr][4 * q + 4][e] = (uint8_t)b3;
        }
    }

    __syncthreads();

    // ---- conv: item = (o-group og, row r, quad qc); 4 px x 16 o each ----
    #pragma unroll
    for (int it = 0; it < 2; ++it) {
        const int item = tid + it * BLK;         // valid < 784
        if (item < CITEMS) {
            const int og = item / 196;           // 0..3
            const int rem = item - og * 196;
            const int r  = rem / 28;             // 0..6 row within band
            const int qc = rem - r * 28;         // 0..27
            const int w0 = 4 * qc;
            const int h  = h0 + r;

            uint64_t A[3][6];                    // tile rows r..r+2 = image h-1..h+1
            #pragma unroll
            for (int rr = 0; rr < 3; ++rr)
                #pragma unroll
                for (int j = 0; j < 6; ++j)
                    A[rr][j] = *(const uint64_t*)&sm[r + rr][w0 + j][0];

            const int ht = (h == 0) ? 0 : ((h == HH - 1) ? 2 : 1);
            const float* bp0  = &basesl[(ht * 3 + ((w0 == 0) ? 0 : 1)) * OO];
            const float* bp12 = &basesl[(ht * 3 + 1) * OO];
            const float* bp3  = &basesl[(ht * 3 + ((w0 + 3 == WW - 1) ? 2 : 1)) * OO];

            float* op = out + (size_t)n * (OO * HW) + (size_t)h * WW + w0;
            const int o0 = og * 16;
            #pragma unroll 2
            for (int o = o0; o < o0 + 16; ++o) {
                const uint64_t* wk = &wlds[o * 9];
                int s0 = 0, s1 = 0, s2 = 0, s3 = 0;
                #pragma unroll
                for (int kh = 0; kh < 3; ++kh) {
                    #pragma unroll
                    for (int kw = 0; kw < 3; ++kw) {
                        const uint64_t wv = wk[kh * 3 + kw];
                        // px j tap kw -> image col w0+j+kw-1 -> tile col w0+j+kw
                        s0 += __popcll(A[kh][kw    ] ^ wv);
                        s1 += __popcll(A[kh][kw + 1] ^ wv);
                        s2 += __popcll(A[kh][kw + 2] ^ wv);
                        s3 += __popcll(A[kh][kw + 3] ^ wv);
                    }
                }
                f4v v;
                v.x = bp0[o]  - 2.0f * (float)s0;
                v.y = bp12[o] - 2.0f * (float)s1;
                v.z = bp12[o] - 2.0f * (float)s2;
                v.w = bp3[o]  - 2.0f * (float)s3;
                *(f4v*)(op + (size_t)o * HW) = v;   // PLAIN store: let L2 merge
            }
        }
    }
}

extern "C" void kernel_launch(void* const* d_in, const int* in_sizes, int n_in,
                              void* d_out, int out_size, void* d_ws, size_t ws_size,
                              hipStream_t stream) {
    const float* act = (const float*)d_in[0];
    const float* wgt = (const float*)d_in[1];
    float* out = (float*)d_out;

    uint64_t* wp = (uint64_t*)d_ws;              // 576 u64
    float* basesg = (float*)(wp + 1024);         // 576 f32

    prepack_kernel<<<1, 576, 0, stream>>>(wgt, wp, basesg);
    fused_kernel<<<GRID, BLK, 0, stream>>>(act, wp, basesg, out);
}